// Round 11
// baseline (87.930 us; speedup 1.0000x reference)
//
#include <hip/hip_runtime.h>

#define NB 8
#define NPTS 4096
#define MC 8                         // m-chunks (512 m each)
#define MTILES 16                    // 32-wide m-tiles per chunk
#define OUT_SCALE (1.0f / (float)(NPTS * NB))

typedef float v2f   __attribute__((ext_vector_type(2)));
typedef short bf8v  __attribute__((ext_vector_type(8)));    // 8 bf16 (4 VGPR)
typedef float f16v  __attribute__((ext_vector_type(16)));   // MFMA acc
typedef unsigned short u16v8 __attribute__((ext_vector_type(8)));

static __device__ inline v2f v2min(v2f a, v2f b) {
#if defined(__has_builtin) && __has_builtin(__builtin_elementwise_min)
    return __builtin_elementwise_min(a, b);
#else
    v2f r; r.x = fminf(a.x, b.x); r.y = fminf(a.y, b.y); return r;
#endif
}
static __device__ inline v2f mk2(float a, float b) { v2f r; r.x = a; r.y = b; return r; }

static __device__ inline unsigned short bh(float f) {       // fp32 -> bf16 RNE
    unsigned u = __float_as_uint(f);
    return (unsigned short)((u + 0x7fff + ((u >> 16) & 1)) >> 16);
}
static __device__ inline float bf(unsigned short h) {
    return __uint_as_float(((unsigned)h) << 16);
}

// ws layout: [arec 1MB][brec 1MB][pmin 1MB][pcol 4MB]
#define AREC_OFF  0
#define BREC_OFF  (1u << 20)
#define PMIN_OFF  (2u << 20)
#define PCOL_OFF  (3u << 20)
#define WS_NEED   (7u << 20)

// K-slot plan for one mfma_f32_32x32x16_bf16 (A from x, B from y):
//  k0..2 : -2xh * yh     k3..5 : -2xl * yh    k6..8 : 1 * yy{1,2,3}
//  k9..11: xx{1,2,3} * 1 k12..14: -2xh * yl   k15: 0
// => D = xx + yy - 2*x.y  (missing 2*xl*yl ~ 2e-4 worst-case, under 1.46e-3 threshold)
#define BONE 0x3F80

__global__ void prep_kernel(const float* __restrict__ x, const float* __restrict__ y,
                            unsigned short* __restrict__ arec,
                            unsigned short* __restrict__ brec,
                            float* __restrict__ out) {
    int idx = blockIdx.x * blockDim.x + threadIdx.x;   // 0 .. 2*NB*NPTS-1
    if (idx == 0) out[0] = 0.0f;
    int set = idx >> 15;
    int r   = idx & 32767;                             // b*NPTS + pt
    int b   = r >> 12;
    int pt  = r & 4095;
    const float* src = (set == 0) ? x : y;
    const float* base = src + (size_t)b * 3 * NPTS + pt;
    float px = base[0], py = base[NPTS], pz = base[2 * NPTS];
    float ss = fmaf(px, px, fmaf(py, py, pz * pz));

    unsigned short hx = bh(px), hy = bh(py), hz = bh(pz);
    unsigned short lx = bh(px - bf(hx)), ly = bh(py - bf(hy)), lz = bh(pz - bf(hz));
    float rr = ss - bf(bh(ss));
    unsigned short s1 = bh(ss), s2 = bh(rr), s3 = bh(rr - bf(s2));

    if (set == 0) {        // A-side (x): -2*hi / -2*lo exactly representable in bf16
        unsigned short nhx = bh(-2.0f * bf(hx)), nhy = bh(-2.0f * bf(hy)), nhz = bh(-2.0f * bf(hz));
        unsigned short nlx = bh(-2.0f * bf(lx)), nly = bh(-2.0f * bf(ly)), nlz = bh(-2.0f * bf(lz));
        u16v8 r0 = {nhx, nhy, nhz, nlx, nly, nlz, BONE, BONE};        // k0..7
        u16v8 r1 = {BONE, s1, s2, s3, nhx, nhy, nhz, 0};              // k8..15
        u16v8* dst = (u16v8*)arec + (size_t)r * 2;
        dst[0] = r0; dst[1] = r1;
    } else {               // B-side (y)
        u16v8 r0 = {hx, hy, hz, hx, hy, hz, s1, s2};                  // k0..7
        u16v8 r1 = {s3, BONE, BONE, BONE, lx, ly, lz, 0};             // k8..15
        u16v8* dst = (u16v8*)brec + (size_t)r * 2;
        dst[0] = r0; dst[1] = r1;
    }
}

// grid (MC, 32 n-blocks, NB), block 256 (4 waves; wave w owns x-tile nb*4+w, 32 rows).
// Each block stages its 512-m chunk of brec (16 KB), scans 16 m-tiles: 1 ds_read_b128
// + 1 MFMA + pk-min epilogue per tile. Row-mins (per-x, dir0) and col-mins (per-y,
// dir1) both come from the single P pass.
__global__ __launch_bounds__(256) void chamfer_mfma(
    const unsigned short* __restrict__ arec, const unsigned short* __restrict__ brec,
    float* __restrict__ pmin, float* __restrict__ pcol) {
    __shared__ float4 bls[512 * 2];      // 16 KB staged B-frags
    __shared__ int    colmn[512];        // per-m col-min (int-compare, P>~0)
    __shared__ float  rowL[128];

    const int mc = blockIdx.x, nb = blockIdx.y, b = blockIdx.z;
    const int tid = threadIdx.x, lane = tid & 63, w = tid >> 6;

    colmn[tid] = 0x7F7FFFFF;
    colmn[tid + 256] = 0x7F7FFFFF;

    const float4* bsrc = (const float4*)(brec + ((size_t)b * NPTS + mc * 512) * 16);
    for (int t = tid; t < 1024; t += 256) bls[t] = bsrc[t];

    // A fragment: x-point = (nb*4+w)*32 + (lane&31); lane reads its 16B half-record.
    const int n = (nb * 4 + w) * 32 + (lane & 31);
    const float4* asrc = (const float4*)(arec + (size_t)b * NPTS * 16);
    float4 af4 = asrc[n * 2 + (lane >> 5)];
    bf8v a = *(const bf8v*)&af4;

    v2f racc[8];
#pragma unroll
    for (int r = 0; r < 8; ++r) racc[r] = mk2(3.4e38f, 3.4e38f);

    const int bbase = (lane & 31) * 2 + (lane >> 5);
    __syncthreads();

#pragma unroll 4
    for (int t = 0; t < MTILES; ++t) {
        float4 bf4 = bls[t * 64 + bbase];
        bf8v bb = *(const bf8v*)&bf4;
        f16v z = {0,0,0,0,0,0,0,0,0,0,0,0,0,0,0,0};
        f16v d = __builtin_amdgcn_mfma_f32_32x32x16_bf16(a, bb, z, 0, 0, 0);
        // per-(row,col) running min over tiles (regs = rows for col=lane&31)
#pragma unroll
        for (int r = 0; r < 8; ++r)
            racc[r] = v2min(racc[r], mk2(d[2 * r], d[2 * r + 1]));
        // col-min: fold 16 regs (rows) in-lane, then lane^32 (other 16 rows, same col)
        v2f q0 = v2min(mk2(d[0],  d[1]),  mk2(d[2],  d[3]));
        v2f q1 = v2min(mk2(d[4],  d[5]),  mk2(d[6],  d[7]));
        v2f q2 = v2min(mk2(d[8],  d[9]),  mk2(d[10], d[11]));
        v2f q3 = v2min(mk2(d[12], d[13]), mk2(d[14], d[15]));
        v2f hh = v2min(v2min(q0, q1), v2min(q2, q3));
        float cm = fminf(hh.x, hh.y);
        cm = fminf(cm, __shfl_xor(cm, 32, 64));
        if (lane < 32) atomicMin(&colmn[t * 32 + lane], __float_as_int(cm));
    }

    // fold row-mins across the 32 cols (xor masks 1..16 stay within each half)
    float rf[16];
#pragma unroll
    for (int r = 0; r < 8; ++r) { rf[2 * r] = racc[r].x; rf[2 * r + 1] = racc[r].y; }
#pragma unroll
    for (int m = 1; m <= 16; m <<= 1) {
#pragma unroll
        for (int r = 0; r < 16; ++r) rf[r] = fminf(rf[r], __shfl_xor(rf[r], m, 64));
    }
    if ((lane & 31) == 0) {
        const int half = lane >> 5;
#pragma unroll
        for (int r = 0; r < 16; ++r) {
            int row = (r & 3) + 8 * (r >> 2) + 4 * half;   // 0..31 within the tile
            rowL[w * 32 + row] = rf[r];
        }
    }
    __syncthreads();

    // pmin [b][mc][4096]; pcol [b][nb][4096]
    if (tid < 128) pmin[((size_t)b * MC + mc) * NPTS + nb * 128 + tid] = rowL[tid];
    const size_t cb = ((size_t)b * 32 + nb) * NPTS + mc * 512;
    pcol[cb + tid]       = __int_as_float(colmn[tid]);
    pcol[cb + tid + 256] = __int_as_float(colmn[tid + 256]);
}

// 65536 threads: first 32768 reduce pmin over MC chunks, rest reduce pcol over 32 n-blocks.
__global__ __launch_bounds__(256) void chamfer_reduce2(
    const float* __restrict__ pmin, const float* __restrict__ pcol,
    float* __restrict__ out) {
    __shared__ float sred[4];
    const int u = blockIdx.x * 256 + threadIdx.x;
    float vm;
    if (u < 32768) {
        const int b = u >> 12, n = u & 4095;
        const float* base = pmin + (size_t)b * MC * NPTS + n;
        vm = base[0];
#pragma unroll
        for (int c = 1; c < MC; ++c) vm = fminf(vm, base[(size_t)c * NPTS]);
    } else {
        const int v = u - 32768;
        const int b = v >> 12, m = v & 4095;
        const float* base = pcol + (size_t)b * 32 * NPTS + m;
        vm = base[0];
#pragma unroll
        for (int c = 1; c < 32; ++c) vm = fminf(vm, base[(size_t)c * NPTS]);
    }
    float s = vm;
#pragma unroll
    for (int off = 32; off > 0; off >>= 1) s += __shfl_down(s, off, 64);
    const int lane = threadIdx.x & 63, wid = threadIdx.x >> 6;
    if (lane == 0) sred[wid] = s;
    __syncthreads();
    if (threadIdx.x == 0)
        atomicAdd(out, (sred[0] + sred[1] + sred[2] + sred[3]) * OUT_SCALE);
}

// ---------------- fallback (tiny ws): slow but correct ----------------
__global__ void zero_out(float* out) { out[0] = 0.0f; }

__global__ __launch_bounds__(256) void chamfer_direct(
    const float* __restrict__ x, const float* __restrict__ y,
    float* __restrict__ out) {
    const int b = blockIdx.y, dir = blockIdx.z;
    const float* A  = (dir == 0) ? x : y;
    const float* Bm = (dir == 0) ? y : x;
    const int i = blockIdx.x * blockDim.x + threadIdx.x;
    const float* abase = A + (size_t)b * 3 * NPTS + i;
    const float ax = abase[0], ay = abase[NPTS], az = abase[2 * NPTS];
    const float* bbase = Bm + (size_t)b * 3 * NPTS;
    float vmin = 3.4e38f;
#pragma unroll 8
    for (int m = 0; m < NPTS; ++m) {
        float dx = ax - bbase[m];
        float dy = ay - bbase[NPTS + m];
        float dz = az - bbase[2 * NPTS + m];
        float t = dx * dx;
        t = fmaf(dy, dy, t);
        t = fmaf(dz, dz, t);
        vmin = fminf(vmin, t);
    }
    float s = vmin;
#pragma unroll
    for (int off = 32; off > 0; off >>= 1) s += __shfl_down(s, off, 64);
    if ((threadIdx.x & 63) == 0) atomicAdd(out, s * OUT_SCALE);
}

extern "C" void kernel_launch(void* const* d_in, const int* in_sizes, int n_in,
                              void* d_out, int out_size, void* d_ws, size_t ws_size,
                              hipStream_t stream) {
    const float* x = (const float*)d_in[0];
    const float* y = (const float*)d_in[1];
    float* out = (float*)d_out;

    if (ws_size >= WS_NEED) {
        unsigned short* arec = (unsigned short*)((char*)d_ws + AREC_OFF);
        unsigned short* brec = (unsigned short*)((char*)d_ws + BREC_OFF);
        float* pmin = (float*)((char*)d_ws + PMIN_OFF);
        float* pcol = (float*)((char*)d_ws + PCOL_OFF);
        prep_kernel<<<dim3((2 * NB * NPTS) / 256), dim3(256), 0, stream>>>(x, y, arec, brec, out);
        chamfer_mfma<<<dim3(MC, 32, NB), dim3(256), 0, stream>>>(arec, brec, pmin, pcol);
        chamfer_reduce2<<<dim3((2 * NB * NPTS) / 256), dim3(256), 0, stream>>>(pmin, pcol, out);
    } else {
        zero_out<<<dim3(1), dim3(1), 0, stream>>>(out);
        chamfer_direct<<<dim3(NPTS / 256, NB, 2), dim3(256), 0, stream>>>(x, y, out);
    }
}

// Round 12
// 83.358 us; speedup vs baseline: 1.0548x; 1.0548x over previous
//
#include <hip/hip_runtime.h>

#define NB 8
#define NPTS 4096
#define MC 8                         // m-chunks (512 m each)
#define MTILES 16                    // 32-wide m-tiles per chunk
#define OUT_SCALE (1.0f / (float)(NPTS * NB))

typedef float v2f   __attribute__((ext_vector_type(2)));
typedef short bf8v  __attribute__((ext_vector_type(8)));    // 8 bf16 (4 VGPR)
typedef float f16v  __attribute__((ext_vector_type(16)));   // MFMA acc
typedef unsigned short u16v8 __attribute__((ext_vector_type(8)));

static __device__ inline v2f v2min(v2f a, v2f b) {
#if defined(__has_builtin) && __has_builtin(__builtin_elementwise_min)
    return __builtin_elementwise_min(a, b);
#else
    v2f r; r.x = fminf(a.x, b.x); r.y = fminf(a.y, b.y); return r;
#endif
}
static __device__ inline v2f mk2(float a, float b) { v2f r; r.x = a; r.y = b; return r; }

static __device__ inline unsigned short bh(float f) {       // fp32 -> bf16 RNE
    unsigned u = __float_as_uint(f);
    return (unsigned short)((u + 0x7fff + ((u >> 16) & 1)) >> 16);
}
static __device__ inline float bf(unsigned short h) {
    return __uint_as_float(((unsigned)h) << 16);
}

// ws layout: [pmin 1MB][pcol 4MB]
#define PMIN_OFF  0
#define PCOL_OFF  (1u << 20)
#define WS_NEED   (5u << 20)

// K-slot plan for one mfma_f32_32x32x16_bf16 (A from x, B from y):
//  k0..2 : -2xh * yh     k3..5 : -2xl * yh    k6..8 : 1 * yy{1,2,3}
//  k9..11: xx{1,2,3} * 1 k12..14: -2xh * yl   k15: 0
// => D = xx + yy - 2*x.y  (missing 2*xl*yl ~ 2e-4 worst-case; verified passing in R11)
#define BONE ((unsigned short)0x3F80)

// grid (MC, 32, NB), block 256 (4 waves; wave w owns x-tile nb*4+w = 32 rows).
// Stages raw y chunk (6KB) -> converts to B-fragments in LDS; A-fragment built in
// registers from raw x. One P pass; row-mins (per-x) + col-mins (per-y) extracted.
__global__ __launch_bounds__(256) void chamfer_mfma(
    const float* __restrict__ x, const float* __restrict__ y,
    float* __restrict__ pmin, float* __restrict__ pcol, float* __restrict__ out) {
    __shared__ float4 bls[1024];         // 16 KB B-frags (built in-place)
    __shared__ int    colmn[512];        // per-m col-min (int-compare)
    __shared__ float  rowL[128];

    const int mc = blockIdx.x, nb = blockIdx.y, b = blockIdx.z;
    const int tid = threadIdx.x, lane = tid & 63, w = tid >> 6;

    if (mc == 0 && nb == 0 && b == 0 && tid == 0) out[0] = 0.0f;
    colmn[tid] = 0x7F7FFFFF;
    colmn[tid + 256] = 0x7F7FFFFF;

    // Stage + convert the 512-m y chunk (coalesced raw loads, 2 points/thread).
    const float* yb = y + (size_t)b * 3 * NPTS + mc * 512;
    for (int m = tid; m < 512; m += 256) {
        float p0 = yb[m], p1 = yb[NPTS + m], p2 = yb[2 * NPTS + m];
        float ss = fmaf(p0, p0, fmaf(p1, p1, p2 * p2));
        unsigned short hx = bh(p0), hy = bh(p1), hz = bh(p2);
        unsigned short lx = bh(p0 - bf(hx)), ly = bh(p1 - bf(hy)), lz = bh(p2 - bf(hz));
        float rr = ss - bf(bh(ss));
        unsigned short s1 = bh(ss), s2 = bh(rr), s3 = bh(rr - bf(s2));
        u16v8 r0 = {hx, hy, hz, hx, hy, hz, s1, s2};
        u16v8 r1 = {s3, BONE, BONE, BONE, lx, ly, lz, 0};
        ((u16v8*)bls)[2 * m]     = r0;
        ((u16v8*)bls)[2 * m + 1] = r1;
    }

    // A fragment in registers: x-point n; lane half (lane>>5) picks k0..7 / k8..15.
    const int n = (nb * 4 + w) * 32 + (lane & 31);
    const float* xb = x + (size_t)b * 3 * NPTS;
    {
        float p0 = xb[n], p1 = xb[NPTS + n], p2 = xb[2 * NPTS + n];
        float ss = fmaf(p0, p0, fmaf(p1, p1, p2 * p2));
        unsigned short hx = bh(p0), hy = bh(p1), hz = bh(p2);
        unsigned short lx = bh(p0 - bf(hx)), ly = bh(p1 - bf(hy)), lz = bh(p2 - bf(hz));
        float rr = ss - bf(bh(ss));
        unsigned short s1 = bh(ss), s2 = bh(rr), s3 = bh(rr - bf(s2));
        unsigned short nhx = bh(-2.0f * bf(hx)), nhy = bh(-2.0f * bf(hy)), nhz = bh(-2.0f * bf(hz));
        unsigned short nlx = bh(-2.0f * bf(lx)), nly = bh(-2.0f * bf(ly)), nlz = bh(-2.0f * bf(lz));
        u16v8 ar;
        const bool lo = (lane < 32);
        ar[0] = lo ? nhx : BONE;
        ar[1] = lo ? nhy : s1;
        ar[2] = lo ? nhz : s2;
        ar[3] = lo ? nlx : s3;
        ar[4] = lo ? nly : nhx;
        ar[5] = lo ? nlz : nhy;
        ar[6] = lo ? BONE : nhz;
        ar[7] = lo ? BONE : (unsigned short)0;
        // stash via union-free bitcast below
        __syncthreads();

        bf8v a = *(bf8v*)&ar;

        v2f racc[8];
#pragma unroll
        for (int r = 0; r < 8; ++r) racc[r] = mk2(3.4e38f, 3.4e38f);

        const int bbase = (lane & 31) * 2 + (lane >> 5);

#pragma unroll 4
        for (int t = 0; t < MTILES; ++t) {
            float4 bf4 = bls[t * 64 + bbase];
            bf8v bb = *(const bf8v*)&bf4;
            f16v z = {0,0,0,0,0,0,0,0,0,0,0,0,0,0,0,0};
            f16v d = __builtin_amdgcn_mfma_f32_32x32x16_bf16(a, bb, z, 0, 0, 0);
            // per-(row,col) running min over tiles (regs = rows for col=lane&31)
#pragma unroll
            for (int r = 0; r < 8; ++r)
                racc[r] = v2min(racc[r], mk2(d[2 * r], d[2 * r + 1]));
            // col-min: fold 16 regs (rows) in-lane, then lane^32 (other rows, same col)
            v2f q0 = v2min(mk2(d[0],  d[1]),  mk2(d[2],  d[3]));
            v2f q1 = v2min(mk2(d[4],  d[5]),  mk2(d[6],  d[7]));
            v2f q2 = v2min(mk2(d[8],  d[9]),  mk2(d[10], d[11]));
            v2f q3 = v2min(mk2(d[12], d[13]), mk2(d[14], d[15]));
            v2f hh = v2min(v2min(q0, q1), v2min(q2, q3));
            float cm = fminf(hh.x, hh.y);
            cm = fminf(cm, __shfl_xor(cm, 32, 64));
            if (lane < 32) atomicMin(&colmn[t * 32 + lane], __float_as_int(cm));
        }

        // fold row-mins across the 32 cols (xor masks 1..16 stay within each half)
        float rf[16];
#pragma unroll
        for (int r = 0; r < 8; ++r) { rf[2 * r] = racc[r].x; rf[2 * r + 1] = racc[r].y; }
#pragma unroll
        for (int m = 1; m <= 16; m <<= 1) {
#pragma unroll
            for (int r = 0; r < 16; ++r) rf[r] = fminf(rf[r], __shfl_xor(rf[r], m, 64));
        }
        if ((lane & 31) == 0) {
            const int half = lane >> 5;
#pragma unroll
            for (int r = 0; r < 16; ++r) {
                int row = (r & 3) + 8 * (r >> 2) + 4 * half;   // 0..31 within tile
                rowL[w * 32 + row] = rf[r];
            }
        }
    }
    __syncthreads();

    // pmin [b][mc][4096]; pcol [b][nb][4096]
    if (tid < 128) pmin[((size_t)b * MC + mc) * NPTS + nb * 128 + tid] = rowL[tid];
    const size_t cb = ((size_t)b * 32 + nb) * NPTS + mc * 512;
    pcol[cb + tid]       = __int_as_float(colmn[tid]);
    pcol[cb + tid + 256] = __int_as_float(colmn[tid + 256]);
}

// 65536 threads: first 32768 reduce pmin over MC chunks, rest reduce pcol over 32 n-blocks.
__global__ __launch_bounds__(256) void chamfer_reduce2(
    const float* __restrict__ pmin, const float* __restrict__ pcol,
    float* __restrict__ out) {
    __shared__ float sred[4];
    const int u = blockIdx.x * 256 + threadIdx.x;
    float vm;
    if (u < 32768) {
        const int b = u >> 12, n = u & 4095;
        const float* base = pmin + (size_t)b * MC * NPTS + n;
        vm = base[0];
#pragma unroll
        for (int c = 1; c < MC; ++c) vm = fminf(vm, base[(size_t)c * NPTS]);
    } else {
        const int v = u - 32768;
        const int b = v >> 12, m = v & 4095;
        const float* base = pcol + (size_t)b * 32 * NPTS + m;
        vm = base[0];
#pragma unroll
        for (int c = 1; c < 32; ++c) vm = fminf(vm, base[(size_t)c * NPTS]);
    }
    float s = vm;
#pragma unroll
    for (int off = 32; off > 0; off >>= 1) s += __shfl_down(s, off, 64);
    const int lane = threadIdx.x & 63, wid = threadIdx.x >> 6;
    if (lane == 0) sred[wid] = s;
    __syncthreads();
    if (threadIdx.x == 0)
        atomicAdd(out, (sred[0] + sred[1] + sred[2] + sred[3]) * OUT_SCALE);
}

// ---------------- fallback (tiny ws): slow but correct ----------------
__global__ void zero_out(float* out) { out[0] = 0.0f; }

__global__ __launch_bounds__(256) void chamfer_direct(
    const float* __restrict__ x, const float* __restrict__ y,
    float* __restrict__ out) {
    const int b = blockIdx.y, dir = blockIdx.z;
    const float* A  = (dir == 0) ? x : y;
    const float* Bm = (dir == 0) ? y : x;
    const int i = blockIdx.x * blockDim.x + threadIdx.x;
    const float* abase = A + (size_t)b * 3 * NPTS + i;
    const float ax = abase[0], ay = abase[NPTS], az = abase[2 * NPTS];
    const float* bbase = Bm + (size_t)b * 3 * NPTS;
    float vmin = 3.4e38f;
#pragma unroll 8
    for (int m = 0; m < NPTS; ++m) {
        float dx = ax - bbase[m];
        float dy = ay - bbase[NPTS + m];
        float dz = az - bbase[2 * NPTS + m];
        float t = dx * dx;
        t = fmaf(dy, dy, t);
        t = fmaf(dz, dz, t);
        vmin = fminf(vmin, t);
    }
    float s = vmin;
#pragma unroll
    for (int off = 32; off > 0; off >>= 1) s += __shfl_down(s, off, 64);
    if ((threadIdx.x & 63) == 0) atomicAdd(out, s * OUT_SCALE);
}

extern "C" void kernel_launch(void* const* d_in, const int* in_sizes, int n_in,
                              void* d_out, int out_size, void* d_ws, size_t ws_size,
                              hipStream_t stream) {
    const float* x = (const float*)d_in[0];
    const float* y = (const float*)d_in[1];
    float* out = (float*)d_out;

    if (ws_size >= WS_NEED) {
        float* pmin = (float*)((char*)d_ws + PMIN_OFF);
        float* pcol = (float*)((char*)d_ws + PCOL_OFF);
        chamfer_mfma<<<dim3(MC, 32, NB), dim3(256), 0, stream>>>(x, y, pmin, pcol, out);
        chamfer_reduce2<<<dim3((2 * NB * NPTS) / 256), dim3(256), 0, stream>>>(pmin, pcol, out);
    } else {
        zero_out<<<dim3(1), dim3(1), 0, stream>>>(out);
        chamfer_direct<<<dim3(NPTS / 256, NB, 2), dim3(256), 0, stream>>>(x, y, out);
    }
}

// Round 13
// 83.106 us; speedup vs baseline: 1.0580x; 1.0030x over previous
//
#include <hip/hip_runtime.h>

#define NB 8
#define NPTS 4096
#define IPT 8                       // a-points per thread (scalar A-side)
#define OUT_SCALE (1.0f / (float)(NPTS * NB))

typedef float v2f __attribute__((ext_vector_type(2)));

#if defined(__has_builtin) && __has_builtin(__builtin_elementwise_fma)
#define V2FMA(a, b, c) __builtin_elementwise_fma((a), (b), (c))
#else
static __device__ inline v2f V2FMA(v2f a, v2f b, v2f c) {
    v2f r; r.x = fmaf(a.x, b.x, c.x); r.y = fmaf(a.y, b.y, c.y); return r;
}
#endif
#if defined(__has_builtin) && __has_builtin(__builtin_elementwise_min)
#define V2MIN(a, b) __builtin_elementwise_min((a), (b))
#else
static __device__ inline v2f V2MIN(v2f a, v2f b) {
    v2f r; r.x = fminf(a.x, b.x); r.y = fminf(a.y, b.y); return r;
}
#endif

static __device__ inline v2f splat2(float s) { v2f r; r.x = s; r.y = s; return r; }

// ---------------- main: grid (NPTS/(256*IPT)=2, NB, 2*CH), block 256 ----------------
// Best-measured configuration (R9, 80.7 us):
//   * LDS packed over m-PAIRS (32B/pair) -> 2 ds_read_b128 per 2-m per wave
//   * depth-1 software pipeline: prefetch m-pair i+1, compute m-pair i
//   * per-wave + per-block start-offset skew on the circular m-scan (anti-convoy)
// d(a,b) = ||a||^2 + [||b||^2 - 2 a.b]; bracket minimized, ||a||^2 added in epilogue.
template <int CH_>
__global__ __launch_bounds__(256) void chamfer_main(
    const float* __restrict__ x, const float* __restrict__ y,
    float* __restrict__ pmin, float* __restrict__ out) {
    constexpr int MCHUNK = NPTS / CH_;
    constexpr int MP = MCHUNK / 2;          // m-pairs; power of 2
    __shared__ alignas(16) v2f qs2[MP * 4];

    const int b   = blockIdx.y;
    const int z   = blockIdx.z;          // 0 .. 2*CH-1
    const int dir = z / CH_;
    const int ch  = z % CH_;
    const int tid = threadIdx.x;

    const float* A = (dir == 0) ? x : y;
    const float* B = (dir == 0) ? y : x;

    // out is re-poisoned before every call; zero it (reduce runs strictly after main).
    if (blockIdx.x == 0 && b == 0 && z == 0 && tid == 0) out[0] = 0.0f;

    // Stage chunk into LDS in m-pair layout. float index: 8*mp + 2*comp + (m&1).
    const float* bb = B + (size_t)b * 3 * NPTS + (size_t)ch * MCHUNK;
    float* qf = (float*)qs2;
    for (int m = tid; m < MCHUNK; m += 256) {
        float bxv = bb[m];
        float byv = bb[NPTS + m];
        float bzv = bb[2 * NPTS + m];
        int base = 8 * (m >> 1) + (m & 1);
        qf[base + 0] = -2.0f * bxv;
        qf[base + 2] = -2.0f * byv;
        qf[base + 4] = -2.0f * bzv;
        qf[base + 6] = bxv * bxv + byv * byv + bzv * bzv;
    }

    // Load IPT a-points, scalar regs (coalesced global reads).
    const int i0 = blockIdx.x * (256 * IPT) + tid;
    const float* ab = A + (size_t)b * 3 * NPTS;
    float ax[IPT], ay[IPT], az[IPT], xx[IPT];
    v2f vmin2[IPT];
#pragma unroll
    for (int k = 0; k < IPT; ++k) {
        int i = i0 + k * 256;
        ax[k] = ab[i];
        ay[k] = ab[NPTS + i];
        az[k] = ab[2 * NPTS + i];
        xx[k] = fmaf(ax[k], ax[k], fmaf(ay[k], ay[k], az[k] * az[k]));
        vmin2[k] = splat2(3.4e38f);
    }
    __syncthreads();

    // Circular scan with skewed start + depth-1 prefetch.
    const float4* qv4 = (const float4*)qs2;
    const int wid = tid >> 6;
    int idx = (wid * (MP / 4) + (z & 1) * (MP / 8) + blockIdx.x * (MP / 16)) & (MP - 1);
    float4 h0 = qv4[2 * idx];
    float4 h1 = qv4[2 * idx + 1];
#pragma unroll 2
    for (int it = 0; it < MP; ++it) {
        const int nidx = (idx + 1) & (MP - 1);
        float4 n0 = qv4[2 * nidx];       // prefetch next m-pair
        float4 n1 = qv4[2 * nidx + 1];
        v2f cx2, cy2, cz2, cw2;
        cx2.x = h0.x; cx2.y = h0.y;
        cy2.x = h0.z; cy2.y = h0.w;
        cz2.x = h1.x; cz2.y = h1.y;
        cw2.x = h1.z; cw2.y = h1.w;
#pragma unroll
        for (int k = 0; k < IPT; ++k) {
            v2f t = V2FMA(splat2(ax[k]), cx2, cw2);   // splats hoisted
            t = V2FMA(splat2(ay[k]), cy2, t);
            t = V2FMA(splat2(az[k]), cz2, t);
            vmin2[k] = V2MIN(vmin2[k], t);
        }
        h0 = n0; h1 = n1; idx = nidx;
    }

    // Epilogue: fold lo/hi, add ||a||^2, write partial mins (coalesced in i).
    float* pout = pmin + ((size_t)(dir * NB + b) * CH_ + ch) * NPTS;
#pragma unroll
    for (int k = 0; k < IPT; ++k) {
        pout[i0 + k * 256] = fminf(vmin2[k].x, vmin2[k].y) + xx[k];
    }
}

// ---------------- reduce: min over CH chunks, sum all, one atomic/block ----------------
template <int CH_>
__global__ __launch_bounds__(256) void chamfer_reduce(
    const float* __restrict__ pmin, float* __restrict__ out) {
    __shared__ float sred[4];
    const int u  = blockIdx.x * 256 + threadIdx.x;     // 0 .. 2*NB*NPTS-1
    const int i  = u & (NPTS - 1);
    const int db = u >> 12;                            // dir*NB+b
    const float* base = pmin + (size_t)db * CH_ * NPTS + i;
    float vm = base[0];
#pragma unroll
    for (int c = 1; c < CH_; ++c) vm = fminf(vm, base[(size_t)c * NPTS]);

    float s = vm;
#pragma unroll
    for (int off = 32; off > 0; off >>= 1) s += __shfl_down(s, off, 64);
    const int lane = threadIdx.x & 63;
    const int wid  = threadIdx.x >> 6;
    if (lane == 0) sred[wid] = s;
    __syncthreads();
    if (threadIdx.x == 0) {
        float tot = sred[0] + sred[1] + sred[2] + sred[3];
        atomicAdd(out, tot * OUT_SCALE);
    }
}

// ---------------- fallback (tiny ws): slow but correct ----------------
__global__ void zero_out(float* out) { out[0] = 0.0f; }

__global__ __launch_bounds__(256) void chamfer_direct(
    const float* __restrict__ x, const float* __restrict__ y,
    float* __restrict__ out) {
    const int b   = blockIdx.y;
    const int dir = blockIdx.z;
    const float* A  = (dir == 0) ? x : y;
    const float* Bm = (dir == 0) ? y : x;
    const int i = blockIdx.x * blockDim.x + threadIdx.x;
    const float* abase = A + (size_t)b * 3 * NPTS + i;
    const float ax = abase[0], ay = abase[NPTS], az = abase[2 * NPTS];
    const float* bbase = Bm + (size_t)b * 3 * NPTS;
    float vmin = 3.4e38f;
#pragma unroll 8
    for (int m = 0; m < NPTS; ++m) {
        float dx = ax - bbase[m];
        float dy = ay - bbase[NPTS + m];
        float dz = az - bbase[2 * NPTS + m];
        float t = dx * dx;
        t = fmaf(dy, dy, t);
        t = fmaf(dz, dz, t);
        vmin = fminf(vmin, t);
    }
    float s = vmin;
#pragma unroll
    for (int off = 32; off > 0; off >>= 1) s += __shfl_down(s, off, 64);
    if ((threadIdx.x & 63) == 0) atomicAdd(out, s * OUT_SCALE);
}

extern "C" void kernel_launch(void* const* d_in, const int* in_sizes, int n_in,
                              void* d_out, int out_size, void* d_ws, size_t ws_size,
                              hipStream_t stream) {
    const float* x = (const float*)d_in[0];
    const float* y = (const float*)d_in[1];
    float* out  = (float*)d_out;
    float* pmin = (float*)d_ws;

    const dim3 blk(256);
    const int gx = NPTS / (256 * IPT);                     // 2

    const size_t need32 = 2ull * NB * 32 * NPTS * sizeof(float);
    const size_t need8  = 2ull * NB * 8  * NPTS * sizeof(float);

    if (ws_size >= need32) {
        chamfer_main<32><<<dim3(gx, NB, 2 * 32), blk, 0, stream>>>(x, y, pmin, out);
        chamfer_reduce<32><<<dim3((2 * NB * NPTS) / 256), blk, 0, stream>>>(pmin, out);
    } else if (ws_size >= need8) {
        chamfer_main<8><<<dim3(gx, NB, 2 * 8), blk, 0, stream>>>(x, y, pmin, out);
        chamfer_reduce<8><<<dim3((2 * NB * NPTS) / 256), blk, 0, stream>>>(pmin, out);
    } else {
        zero_out<<<dim3(1), dim3(1), 0, stream>>>(out);
        chamfer_direct<<<dim3(NPTS / 256, NB, 2), blk, 0, stream>>>(x, y, out);
    }
}